// Round 3
// baseline (487.595 us; speedup 1.0000x reference)
//
#include <hip/hip_runtime.h>
#include <hip/hip_bf16.h>

// Problem constants (B=8, Tq=Tv=512, D=512, U=128)
constexpr int Bb = 8;
constexpr int Tq = 512;
constexpr int Tv = 512;
constexpr int Dd = 512;
constexpr int Uu = 128;

// ---------------------------------------------------------------------------
// Kernel M: canonicalize mask into int[4096] in workspace (handles int32 /
// uint8 / bf16 / fp32 storage of the bool mask; identity if already int32).
// ---------------------------------------------------------------------------
__global__ __launch_bounds__(256) void mask_canon_kernel(
    const unsigned char* __restrict__ mraw, int* __restrict__ mout)
{
    const int N = Bb * Tv;            // 4096
    const int t = threadIdx.x;
    __shared__ unsigned int f_or123, f_gt1, f_or1;
    if (t == 0) { f_or123 = 0u; f_gt1 = 0u; f_or1 = 0u; }
    __syncthreads();
    unsigned int l123 = 0, lgt1 = 0, l1 = 0;
    for (int i = t; i < N; i += 256) {
        unsigned char c = mraw[i];
        const int m4 = i & 3;
        if (m4 != 0) l123 |= c;
        if (m4 == 1) l1 |= c;
        if (c > 1u)  lgt1 = 1u;
    }
    if (l123) atomicOr(&f_or123, l123);
    if (lgt1) atomicOr(&f_gt1, lgt1);
    if (l1)   atomicOr(&f_or1, l1);
    __syncthreads();
    const bool is_i32 = (f_or123 == 0u);
    const bool is_u8  = !is_i32 && (f_gt1 == 0u);
    const bool is_b16 = !is_i32 && !is_u8 && (f_or1 != 0u);
    for (int i = t; i < N; i += 256) {
        int v;
        if (is_i32)      v = (((const int*)mraw)[i] != 0);
        else if (is_u8)  v = (mraw[i] != 0);
        else if (is_b16) v = (((const unsigned short*)mraw)[i] != 0);
        else             v = (((const float*)mraw)[i] != 0.f);
        mout[i] = v;
    }
}

// ---------------------------------------------------------------------------
// Kernel A: fused projections  qf = query @ Wa,  kf = key @ Ua   (fp32)
// grid = 2*B*Tq blocks of 128 threads; block 'bid' handles one row.
// ---------------------------------------------------------------------------
__global__ __launch_bounds__(128) void proj_kernel(
    const float* __restrict__ query,
    const float* __restrict__ key,
    const float* __restrict__ Wa,
    const float* __restrict__ Ua,
    float* __restrict__ qf, float* __restrict__ kf)
{
    const int bid   = blockIdx.x;
    const int nrows = Bb * Tq;                 // 4096
    const bool isQ  = bid < nrows;
    const int row   = isQ ? bid : bid - nrows;
    const float* __restrict__ src = isQ ? query : key;
    const float* __restrict__ W   = isQ ? Wa : Ua;
    float* __restrict__ dst = isQ ? qf : kf;

    __shared__ float xrow[Dd];
    // 512 floats = 128 float4; one per thread, coalesced
    reinterpret_cast<float4*>(xrow)[threadIdx.x] =
        reinterpret_cast<const float4*>(src + row * Dd)[threadIdx.x];
    __syncthreads();

    const int u = threadIdx.x;                 // 0..127  (one output unit each)
    float acc = 0.f;
#pragma unroll 8
    for (int d = 0; d < Dd; ++d)
        acc = fmaf(xrow[d], W[d * Uu + u], acc);
    dst[row * Uu + u] = acc;
}

// fast tanh: tanh(x) = (e^{2x}-1)/(e^{2x}+1), e^{2x} = 2^{x*2/ln2}
__device__ __forceinline__ float fast_tanh(float x)
{
    float e = __builtin_amdgcn_exp2f(fminf(x * 2.88539008177f, 126.f));
    return (e - 1.f) * __builtin_amdgcn_rcpf(e + 1.f);
}

// ---------------------------------------------------------------------------
// Kernel B: per query-row attention.  grid = B*Tq blocks of 256 threads.
//   scores_j = sum_u scale_u * tanh(q_u + k_ju)  (mask -> -1e9)
//   softmax over j, then context_d = sum_j w_j * value[j,d]
// ---------------------------------------------------------------------------
__global__ __launch_bounds__(256) void attn_kernel(
    const float* __restrict__ qf, const float* __restrict__ kf,
    const float* __restrict__ value,
    const int* __restrict__ mask,
    const float* __restrict__ scale,
    float* __restrict__ out)
{
    const int bi = blockIdx.x;        // b*Tq + i
    const int b  = bi >> 9;           // /512
    const int t  = threadIdx.x;       // 0..255

    __shared__ float qrow[Uu];
    __shared__ float sscale[Uu];
    __shared__ float w[Tv];
    __shared__ float redbuf[8];

    if (t < Uu) {
        qrow[t]   = qf[bi * Uu + t];
        sscale[t] = scale[t];
    }
    __syncthreads();

    // ---- scores: each thread handles j = t and j = t+256 ----
    float sc[2];
#pragma unroll
    for (int r = 0; r < 2; ++r) {
        const int j = t + r * 256;
        const float4* __restrict__ kr =
            reinterpret_cast<const float4*>(kf + (b * Tv + j) * Uu);
        float s = 0.f;
#pragma unroll 4
        for (int u4 = 0; u4 < Uu / 4; ++u4) {
            float4 kv = kr[u4];
            const float* qp = &qrow[u4 * 4];
            const float* sp = &sscale[u4 * 4];
            s = fmaf(sp[0], fast_tanh(qp[0] + kv.x), s);
            s = fmaf(sp[1], fast_tanh(qp[1] + kv.y), s);
            s = fmaf(sp[2], fast_tanh(qp[2] + kv.z), s);
            s = fmaf(sp[3], fast_tanh(qp[3] + kv.w), s);
        }
        sc[r] = mask[b * Tv + j] ? s : -1e9f;
    }

    // ---- block max reduction ----
    float m = fmaxf(sc[0], sc[1]);
#pragma unroll
    for (int off = 32; off > 0; off >>= 1) m = fmaxf(m, __shfl_down(m, off, 64));
    if ((t & 63) == 0) redbuf[t >> 6] = m;
    __syncthreads();
    m = fmaxf(fmaxf(redbuf[0], redbuf[1]), fmaxf(redbuf[2], redbuf[3]));

    // ---- exp + block sum reduction ----
    float e0 = __builtin_amdgcn_exp2f((sc[0] - m) * 1.44269504089f);
    float e1 = __builtin_amdgcn_exp2f((sc[1] - m) * 1.44269504089f);
    w[t] = e0; w[t + 256] = e1;
    float s = e0 + e1;
#pragma unroll
    for (int off = 32; off > 0; off >>= 1) s += __shfl_down(s, off, 64);
    if ((t & 63) == 0) redbuf[4 + (t >> 6)] = s;
    __syncthreads();
    const float inv = 1.0f / (redbuf[4] + redbuf[5] + redbuf[6] + redbuf[7]);

    // ---- context: thread t handles d = 2t, 2t+1 (coalesced float2 loads) ----
    const float* __restrict__ vb = value + b * Tv * Dd;
    const int d0 = 2 * t;
    float a0 = 0.f, a1 = 0.f;
#pragma unroll 4
    for (int j = 0; j < Tv; ++j) {
        float wj = w[j];
        float2 v2 = *reinterpret_cast<const float2*>(vb + j * Dd + d0);
        a0 = fmaf(wj, v2.x, a0);
        a1 = fmaf(wj, v2.y, a1);
    }
    float2 o; o.x = a0 * inv; o.y = a1 * inv;
    *reinterpret_cast<float2*>(out + bi * Dd + d0) = o;
}

extern "C" void kernel_launch(void* const* d_in, const int* in_sizes, int n_in,
                              void* d_out, int out_size, void* d_ws, size_t ws_size,
                              hipStream_t stream)
{
    const float* query = (const float*)d_in[0];
    const float* key   = (const float*)d_in[1];
    const float* value = (const float*)d_in[2];
    const unsigned char* mraw = (const unsigned char*)d_in[3];
    const float* Wa    = (const float*)d_in[4];
    const float* Ua    = (const float*)d_in[5];
    const float* scale = (const float*)d_in[6];
    float* out = (float*)d_out;

    float* qf    = (float*)d_ws;                  // [B*Tq, U]  = 2 MB
    float* kf    = qf + Bb * Tq * Uu;             // [B*Tv, U]  = 2 MB
    int*   maskc = (int*)(kf + Bb * Tv * Uu);     // [B*Tv]     = 16 KB

    mask_canon_kernel<<<1, 256, 0, stream>>>(mraw, maskc);
    proj_kernel<<<2 * Bb * Tq, 128, 0, stream>>>(query, key, Wa, Ua, qf, kf);
    attn_kernel<<<Bb * Tq, 256, 0, stream>>>(qf, kf, value, maskc, scale, out);
}

// Round 4
// 213.922 us; speedup vs baseline: 2.2793x; 2.2793x over previous
//
#include <hip/hip_runtime.h>

// Problem constants (B=8, Tq=Tv=512, D=512, U=128)
constexpr int Bb = 8;
constexpr int Tq = 512;
constexpr int Tv = 512;
constexpr int Dd = 512;
constexpr int Uu = 128;
constexpr float C2LOG2E = 2.88539008177792681f;   // 2*log2(e)
constexpr float LOG2E   = 1.44269504088896341f;

// ---------------------------------------------------------------------------
// Kernel M: canonicalize mask into int[4096] (proved identity-safe for int32;
// keeps us robust to uint8/bf16/fp32 bool storage).
// ---------------------------------------------------------------------------
__global__ __launch_bounds__(256) void mask_canon_kernel(
    const unsigned char* __restrict__ mraw, int* __restrict__ mout)
{
    const int N = Bb * Tv;
    const int t = threadIdx.x;
    __shared__ unsigned int f_or123, f_gt1, f_or1;
    if (t == 0) { f_or123 = 0u; f_gt1 = 0u; f_or1 = 0u; }
    __syncthreads();
    unsigned int l123 = 0, lgt1 = 0, l1 = 0;
    for (int i = t; i < N; i += 256) {
        unsigned char c = mraw[i];
        const int m4 = i & 3;
        if (m4 != 0) l123 |= c;
        if (m4 == 1) l1 |= c;
        if (c > 1u)  lgt1 = 1u;
    }
    if (l123) atomicOr(&f_or123, l123);
    if (lgt1) atomicOr(&f_gt1, lgt1);
    if (l1)   atomicOr(&f_or1, l1);
    __syncthreads();
    const bool is_i32 = (f_or123 == 0u);
    const bool is_u8  = !is_i32 && (f_gt1 == 0u);
    const bool is_b16 = !is_i32 && !is_u8 && (f_or1 != 0u);
    for (int i = t; i < N; i += 256) {
        int v;
        if (is_i32)      v = (((const int*)mraw)[i] != 0);
        else if (is_u8)  v = (mraw[i] != 0);
        else if (is_b16) v = (((const unsigned short*)mraw)[i] != 0);
        else             v = (((const float*)mraw)[i] != 0.f);
        mout[i] = v;
    }
}

// ---------------------------------------------------------------------------
// Kernel A: projections, 16 rows per block.  Writes q/k premultiplied by
// 2*log2(e) so the score kernel's exp2 argument is a single add.
// grid = 512 blocks of 256 threads (blocks 0..255 -> query/Wa, 256..511 -> key/Ua)
// ---------------------------------------------------------------------------
__global__ __launch_bounds__(256) void proj_kernel(
    const float* __restrict__ query,
    const float* __restrict__ key,
    const float* __restrict__ Wa,
    const float* __restrict__ Ua,
    float* __restrict__ qf2, float* __restrict__ kf2)
{
    const int R    = blockIdx.x * 16;              // global row base (0..8191)
    const bool isQ = R < Bb * Tq;
    const float* __restrict__ src = isQ ? query : key;
    const float* __restrict__ W   = isQ ? Wa : Ua;
    float* __restrict__ dst       = isQ ? qf2 : kf2;
    const int Rloc = isQ ? R : R - Bb * Tq;

    __shared__ float x[16 * Dd];                   // 32 KB
    const int t = threadIdx.x;

    // stage 16 input rows: 2048 float4, coalesced
    {
        const float4* __restrict__ s4 =
            reinterpret_cast<const float4*>(src + (size_t)Rloc * Dd);
        float4* x4 = reinterpret_cast<float4*>(x);
#pragma unroll
        for (int m = 0; m < 8; ++m) x4[t + 256 * m] = s4[t + 256 * m];
    }
    __syncthreads();

    const int u  = t & 127;
    const int rh = t >> 7;                         // 0/1 -> rows rh*8..rh*8+7
    float acc[8] = {0,0,0,0,0,0,0,0};

#pragma unroll 2
    for (int d4 = 0; d4 < Dd / 4; ++d4) {
        const int d = d4 * 4;
        const float wv0 = W[(d + 0) * Uu + u];
        const float wv1 = W[(d + 1) * Uu + u];
        const float wv2 = W[(d + 2) * Uu + u];
        const float wv3 = W[(d + 3) * Uu + u];
#pragma unroll
        for (int k = 0; k < 8; ++k) {
            float4 xv = *reinterpret_cast<const float4*>(x + (rh * 8 + k) * Dd + d);
            acc[k] = fmaf(xv.x, wv0, acc[k]);
            acc[k] = fmaf(xv.y, wv1, acc[k]);
            acc[k] = fmaf(xv.z, wv2, acc[k]);
            acc[k] = fmaf(xv.w, wv3, acc[k]);
        }
    }
#pragma unroll
    for (int k = 0; k < 8; ++k)
        dst[(size_t)(Rloc + rh * 8 + k) * Uu + u] = C2LOG2E * acc[k];
}

// ---------------------------------------------------------------------------
// Kernel B: attention, 8 query rows per block, 512 threads.
//   score phase : thread t <-> key j=t; 8 accumulators (one per query row).
//                 tanh folded: score_i = S + sum_u s2_u * rcp(1 + exp2(q2+k2))
//                 with q2,k2 premultiplied by 2*log2e, s2 = -2*scale, S = sum(scale)
//   softmax     : wave wv reduces row wv (8 waves <-> 8 rows)
//   context     : thread (ti=t>>7, td=t&127) owns rows {ti, ti+4}, d = 4*td..+3
// ---------------------------------------------------------------------------
__global__ __launch_bounds__(512) void attn_kernel(
    const float* __restrict__ qf2, const float* __restrict__ kf2,
    const float* __restrict__ value,
    const int* __restrict__ mask,
    const float* __restrict__ scale,
    float* __restrict__ out)
{
    const int r0 = blockIdx.x * 8;            // first global query row (0..4095)
    const int b  = r0 >> 9;                   // batch
    const int t  = threadIdx.x;               // 0..511

    __shared__ float q2[8 * Uu];              // 4 KB   (premultiplied q rows)
    __shared__ float s2[Uu];                  // -2*scale
    __shared__ float w[8 * Tv];               // 16 KB  scores -> weights
    __shared__ float inv8[8];
    __shared__ float Ssum;

    if (t < 256)
        reinterpret_cast<float4*>(q2)[t] =
            reinterpret_cast<const float4*>(qf2 + (size_t)r0 * Uu)[t];
    if (t >= 256 && t < 384) { const int u = t - 256; s2[u] = -2.f * scale[u]; }
    if (t < 64) {
        float v = scale[t] + scale[t + 64];
#pragma unroll
        for (int off = 32; off; off >>= 1) v += __shfl_xor(v, off, 64);
        if (t == 0) Ssum = v;
    }
    __syncthreads();

    // ---- scores ----
    const int j = t;
    const float4* __restrict__ kr =
        reinterpret_cast<const float4*>(kf2 + (size_t)(b * Tv + j) * Uu);
    float acc[8] = {0,0,0,0,0,0,0,0};
#pragma unroll 2
    for (int u4 = 0; u4 < Uu / 4; ++u4) {
        const float4 kv = kr[u4];
        const float4 sv = reinterpret_cast<const float4*>(s2)[u4];
#pragma unroll
        for (int i = 0; i < 8; ++i) {
            const float4 qv = *reinterpret_cast<const float4*>(q2 + i * Uu + u4 * 4);
            float e0 = __builtin_amdgcn_exp2f(qv.x + kv.x);
            float e1 = __builtin_amdgcn_exp2f(qv.y + kv.y);
            float e2 = __builtin_amdgcn_exp2f(qv.z + kv.z);
            float e3 = __builtin_amdgcn_exp2f(qv.w + kv.w);
            acc[i] = fmaf(sv.x, __builtin_amdgcn_rcpf(e0 + 1.f), acc[i]);
            acc[i] = fmaf(sv.y, __builtin_amdgcn_rcpf(e1 + 1.f), acc[i]);
            acc[i] = fmaf(sv.z, __builtin_amdgcn_rcpf(e2 + 1.f), acc[i]);
            acc[i] = fmaf(sv.w, __builtin_amdgcn_rcpf(e3 + 1.f), acc[i]);
        }
    }
    {
        const float S  = Ssum;
        const int   mk = mask[b * Tv + j];
#pragma unroll
        for (int i = 0; i < 8; ++i)
            w[i * Tv + j] = mk ? (S + acc[i]) : -1e9f;
    }
    __syncthreads();

    // ---- softmax: wave wv handles row wv ----
    {
        const int wv = t >> 6, ln = t & 63;
        float* __restrict__ row = w + wv * Tv;
        float vals[8];
        float m = -3e38f;
#pragma unroll
        for (int c = 0; c < 8; ++c) { vals[c] = row[ln + 64 * c]; m = fmaxf(m, vals[c]); }
#pragma unroll
        for (int off = 32; off; off >>= 1) m = fmaxf(m, __shfl_xor(m, off, 64));
        float sum = 0.f;
#pragma unroll
        for (int c = 0; c < 8; ++c) {
            float e = __builtin_amdgcn_exp2f((vals[c] - m) * LOG2E);
            row[ln + 64 * c] = e;
            sum += e;
        }
#pragma unroll
        for (int off = 32; off; off >>= 1) sum += __shfl_xor(sum, off, 64);
        if (ln == 0) inv8[wv] = 1.0f / sum;
    }
    __syncthreads();

    // ---- context ----
    const int ti = t >> 7;                 // 0..3
    const int td = t & 127;
    const int d0 = td * 4;
    const int i0 = ti, i1 = ti + 4;
    const float* __restrict__ vb = value + (size_t)b * Tv * Dd + d0;
    float4 a0 = {0,0,0,0}, a1 = {0,0,0,0};
#pragma unroll 2
    for (int j4 = 0; j4 < Tv / 4; ++j4) {
        const float4 w0 = *reinterpret_cast<const float4*>(w + i0 * Tv + j4 * 4);
        const float4 w1 = *reinterpret_cast<const float4*>(w + i1 * Tv + j4 * 4);
        const float4 v0 = *reinterpret_cast<const float4*>(vb + (size_t)(j4 * 4 + 0) * Dd);
        const float4 v1 = *reinterpret_cast<const float4*>(vb + (size_t)(j4 * 4 + 1) * Dd);
        const float4 v2 = *reinterpret_cast<const float4*>(vb + (size_t)(j4 * 4 + 2) * Dd);
        const float4 v3 = *reinterpret_cast<const float4*>(vb + (size_t)(j4 * 4 + 3) * Dd);
        a0.x = fmaf(w0.x, v0.x, a0.x); a0.y = fmaf(w0.x, v0.y, a0.y);
        a0.z = fmaf(w0.x, v0.z, a0.z); a0.w = fmaf(w0.x, v0.w, a0.w);
        a1.x = fmaf(w1.x, v0.x, a1.x); a1.y = fmaf(w1.x, v0.y, a1.y);
        a1.z = fmaf(w1.x, v0.z, a1.z); a1.w = fmaf(w1.x, v0.w, a1.w);
        a0.x = fmaf(w0.y, v1.x, a0.x); a0.y = fmaf(w0.y, v1.y, a0.y);
        a0.z = fmaf(w0.y, v1.z, a0.z); a0.w = fmaf(w0.y, v1.w, a0.w);
        a1.x = fmaf(w1.y, v1.x, a1.x); a1.y = fmaf(w1.y, v1.y, a1.y);
        a1.z = fmaf(w1.y, v1.z, a1.z); a1.w = fmaf(w1.y, v1.w, a1.w);
        a0.x = fmaf(w0.z, v2.x, a0.x); a0.y = fmaf(w0.z, v2.y, a0.y);
        a0.z = fmaf(w0.z, v2.z, a0.z); a0.w = fmaf(w0.z, v2.w, a0.w);
        a1.x = fmaf(w1.z, v2.x, a1.x); a1.y = fmaf(w1.z, v2.y, a1.y);
        a1.z = fmaf(w1.z, v2.z, a1.z); a1.w = fmaf(w1.z, v2.w, a1.w);
        a0.x = fmaf(w0.w, v3.x, a0.x); a0.y = fmaf(w0.w, v3.y, a0.y);
        a0.z = fmaf(w0.w, v3.z, a0.z); a0.w = fmaf(w0.w, v3.w, a0.w);
        a1.x = fmaf(w1.w, v3.x, a1.x); a1.y = fmaf(w1.w, v3.y, a1.y);
        a1.z = fmaf(w1.w, v3.z, a1.z); a1.w = fmaf(w1.w, v3.w, a1.w);
    }
    const float iv0 = inv8[i0], iv1 = inv8[i1];
    float4 o0, o1;
    o0.x = a0.x * iv0; o0.y = a0.y * iv0; o0.z = a0.z * iv0; o0.w = a0.w * iv0;
    o1.x = a1.x * iv1; o1.y = a1.y * iv1; o1.z = a1.z * iv1; o1.w = a1.w * iv1;
    *reinterpret_cast<float4*>(out + (size_t)(r0 + i0) * Dd + d0) = o0;
    *reinterpret_cast<float4*>(out + (size_t)(r0 + i1) * Dd + d0) = o1;
}

extern "C" void kernel_launch(void* const* d_in, const int* in_sizes, int n_in,
                              void* d_out, int out_size, void* d_ws, size_t ws_size,
                              hipStream_t stream)
{
    const float* query = (const float*)d_in[0];
    const float* key   = (const float*)d_in[1];
    const float* value = (const float*)d_in[2];
    const unsigned char* mraw = (const unsigned char*)d_in[3];
    const float* Wa    = (const float*)d_in[4];
    const float* Ua    = (const float*)d_in[5];
    const float* scale = (const float*)d_in[6];
    float* out = (float*)d_out;

    float* qf2   = (float*)d_ws;                  // [4096,128] = 2 MB (premult)
    float* kf2   = qf2 + Bb * Tq * Uu;            // [4096,128] = 2 MB (premult)
    int*   maskc = (int*)(kf2 + Bb * Tv * Uu);    // [4096]     = 16 KB

    mask_canon_kernel<<<1, 256, 0, stream>>>(mraw, maskc);
    proj_kernel<<<(2 * Bb * Tq) / 16, 256, 0, stream>>>(query, key, Wa, Ua, qf2, kf2);
    attn_kernel<<<(Bb * Tq) / 8, 512, 0, stream>>>(qf2, kf2, value, maskc, scale, out);
}

// Round 5
// 194.205 us; speedup vs baseline: 2.5107x; 1.1015x over previous
//
#include <hip/hip_runtime.h>

// Problem constants (B=8, Tq=Tv=512, D=512, U=128)
constexpr int Bb = 8;
constexpr int Tq = 512;
constexpr int Tv = 512;
constexpr int Dd = 512;
constexpr int Uu = 128;
constexpr float C2LOG2E = 2.88539008177792681f;   // 2*log2(e)
constexpr float LOG2E   = 1.44269504088896341f;

// ---------------------------------------------------------------------------
// Kernel A: projections, 16 rows/block, 256 threads.
//   q half: writes qf2[row][u]   = 2*log2e * (query . Wa)   (row-major)
//   k half: writes kT[b][u][j]   = 2*log2e * (key . Ua)     (TRANSPOSED so the
//           attention score loop reads j-contiguous = coalesced)
// Thread t: ub = t&63 -> u columns {ub, ub+64}; rh = t>>6 -> rows rh*4..rh*4+3.
// ---------------------------------------------------------------------------
__global__ __launch_bounds__(256) void proj_kernel(
    const float* __restrict__ query,
    const float* __restrict__ key,
    const float* __restrict__ Wa,
    const float* __restrict__ Ua,
    float* __restrict__ qf2, float* __restrict__ kT)
{
    const int R    = blockIdx.x * 16;              // 0..8191
    const bool isQ = R < Bb * Tq;
    const float* __restrict__ src = isQ ? query : key;
    const float* __restrict__ W   = isQ ? Wa : Ua;
    const int Rloc = isQ ? R : R - Bb * Tq;        // 0..4095

    __shared__ float x[16 * Dd];                   // 32 KB
    const int t = threadIdx.x;

    {   // stage 16 rows (contiguous; 16 | 512 so never straddles a batch)
        const float4* __restrict__ s4 =
            reinterpret_cast<const float4*>(src + (size_t)Rloc * Dd);
        float4* x4 = reinterpret_cast<float4*>(x);
#pragma unroll
        for (int m = 0; m < 8; ++m) x4[t + 256 * m] = s4[t + 256 * m];
    }
    __syncthreads();

    const int ub = t & 63;
    const int rh = t >> 6;                         // 0..3
    float acc[4][2] = {{0,0},{0,0},{0,0},{0,0}};

#pragma unroll 2
    for (int d4 = 0; d4 < Dd / 4; ++d4) {
        const int d = d4 * 4;
        const float w0x = W[(d + 0) * Uu + ub],      w1x = W[(d + 0) * Uu + ub + 64];
        const float w0y = W[(d + 1) * Uu + ub],      w1y = W[(d + 1) * Uu + ub + 64];
        const float w0z = W[(d + 2) * Uu + ub],      w1z = W[(d + 2) * Uu + ub + 64];
        const float w0w = W[(d + 3) * Uu + ub],      w1w = W[(d + 3) * Uu + ub + 64];
#pragma unroll
        for (int k = 0; k < 4; ++k) {
            const float4 xv = *reinterpret_cast<const float4*>(x + (rh * 4 + k) * Dd + d);
            acc[k][0] = fmaf(xv.x, w0x, acc[k][0]);
            acc[k][0] = fmaf(xv.y, w0y, acc[k][0]);
            acc[k][0] = fmaf(xv.z, w0z, acc[k][0]);
            acc[k][0] = fmaf(xv.w, w0w, acc[k][0]);
            acc[k][1] = fmaf(xv.x, w1x, acc[k][1]);
            acc[k][1] = fmaf(xv.y, w1y, acc[k][1]);
            acc[k][1] = fmaf(xv.z, w1z, acc[k][1]);
            acc[k][1] = fmaf(xv.w, w1w, acc[k][1]);
        }
    }

    if (isQ) {
#pragma unroll
        for (int k = 0; k < 4; ++k) {
            const size_t row = (size_t)(Rloc + rh * 4 + k);
            qf2[row * Uu + ub]      = C2LOG2E * acc[k][0];
            qf2[row * Uu + ub + 64] = C2LOG2E * acc[k][1];
        }
    } else {
        const int b  = Rloc >> 9;
        const int j0 = Rloc & 511;
        float* __restrict__ kb = kT + (size_t)b * Uu * Tv;
#pragma unroll
        for (int k = 0; k < 4; ++k) {
            const int j = j0 + rh * 4 + k;
            kb[(size_t)ub        * Tv + j] = C2LOG2E * acc[k][0];
            kb[(size_t)(ub + 64) * Tv + j] = C2LOG2E * acc[k][1];
        }
    }
}

// ---------------------------------------------------------------------------
// Kernel B: attention, 8 query rows/block, 512 threads, thread t <-> key j=t.
//   score_i(j) = S + sum_u s2_u * rcp(1 + exp2(q2[i][u] + kT[u][j]))
//   kT loads are j-contiguous (coalesced); q2/s2 are LDS broadcasts.
// ---------------------------------------------------------------------------
__global__ __launch_bounds__(512) void attn_kernel(
    const float* __restrict__ qf2, const float* __restrict__ kT,
    const float* __restrict__ value,
    const int* __restrict__ mask,
    const float* __restrict__ scale,
    float* __restrict__ out)
{
    const int r0 = blockIdx.x * 8;            // first query row (0..4095)
    const int b  = r0 >> 9;
    const int t  = threadIdx.x;               // 0..511

    __shared__ float q2[8 * Uu];              // 4 KB
    __shared__ float s2[Uu];
    __shared__ float w[8 * Tv];               // 16 KB
    __shared__ float inv8[8];
    __shared__ float Ssum;

    if (t < 256)
        reinterpret_cast<float4*>(q2)[t] =
            reinterpret_cast<const float4*>(qf2 + (size_t)r0 * Uu)[t];
    if (t >= 256 && t < 384) { const int u = t - 256; s2[u] = -2.f * scale[u]; }
    if (t < 64) {
        float v = scale[t] + scale[t + 64];
#pragma unroll
        for (int off = 32; off; off >>= 1) v += __shfl_xor(v, off, 64);
        if (t == 0) Ssum = v;
    }
    __syncthreads();

    // ---- scores ----
    const int j = t;
    const float* __restrict__ kb = kT + (size_t)b * Uu * Tv + j;
    float acc[8] = {0,0,0,0,0,0,0,0};
#pragma unroll 2
    for (int u4 = 0; u4 < Uu / 4; ++u4) {
        const float kx = kb[(size_t)(u4 * 4 + 0) * Tv];
        const float ky = kb[(size_t)(u4 * 4 + 1) * Tv];
        const float kz = kb[(size_t)(u4 * 4 + 2) * Tv];
        const float kw = kb[(size_t)(u4 * 4 + 3) * Tv];
        const float4 sv = reinterpret_cast<const float4*>(s2)[u4];
#pragma unroll
        for (int i = 0; i < 8; ++i) {
            const float4 qv = *reinterpret_cast<const float4*>(q2 + i * Uu + u4 * 4);
            float e0 = __builtin_amdgcn_exp2f(qv.x + kx);
            float e1 = __builtin_amdgcn_exp2f(qv.y + ky);
            float e2 = __builtin_amdgcn_exp2f(qv.z + kz);
            float e3 = __builtin_amdgcn_exp2f(qv.w + kw);
            acc[i] = fmaf(sv.x, __builtin_amdgcn_rcpf(e0 + 1.f), acc[i]);
            acc[i] = fmaf(sv.y, __builtin_amdgcn_rcpf(e1 + 1.f), acc[i]);
            acc[i] = fmaf(sv.z, __builtin_amdgcn_rcpf(e2 + 1.f), acc[i]);
            acc[i] = fmaf(sv.w, __builtin_amdgcn_rcpf(e3 + 1.f), acc[i]);
        }
    }
    {
        const float S  = Ssum;
        const int   mk = mask[b * Tv + j];
#pragma unroll
        for (int i = 0; i < 8; ++i)
            w[i * Tv + j] = mk ? (S + acc[i]) : -1e9f;
    }
    __syncthreads();

    // ---- softmax: wave wv handles row wv ----
    {
        const int wv = t >> 6, ln = t & 63;
        float* __restrict__ row = w + wv * Tv;
        float vals[8];
        float m = -3e38f;
#pragma unroll
        for (int c = 0; c < 8; ++c) { vals[c] = row[ln + 64 * c]; m = fmaxf(m, vals[c]); }
#pragma unroll
        for (int off = 32; off; off >>= 1) m = fmaxf(m, __shfl_xor(m, off, 64));
        float sum = 0.f;
#pragma unroll
        for (int c = 0; c < 8; ++c) {
            float e = __builtin_amdgcn_exp2f((vals[c] - m) * LOG2E);
            row[ln + 64 * c] = e;
            sum += e;
        }
#pragma unroll
        for (int off = 32; off; off >>= 1) sum += __shfl_xor(sum, off, 64);
        if (ln == 0) inv8[wv] = 1.0f / sum;
    }
    __syncthreads();

    // ---- context ----
    const int ti = t >> 7;                 // 0..3
    const int td = t & 127;
    const int d0 = td * 4;
    const int i0 = ti, i1 = ti + 4;
    const float* __restrict__ vb = value + (size_t)b * Tv * Dd + d0;
    float4 a0 = {0,0,0,0}, a1 = {0,0,0,0};
#pragma unroll 2
    for (int j4 = 0; j4 < Tv / 4; ++j4) {
        const float4 w0 = *reinterpret_cast<const float4*>(w + i0 * Tv + j4 * 4);
        const float4 w1 = *reinterpret_cast<const float4*>(w + i1 * Tv + j4 * 4);
        const float4 v0 = *reinterpret_cast<const float4*>(vb + (size_t)(j4 * 4 + 0) * Dd);
        const float4 v1 = *reinterpret_cast<const float4*>(vb + (size_t)(j4 * 4 + 1) * Dd);
        const float4 v2 = *reinterpret_cast<const float4*>(vb + (size_t)(j4 * 4 + 2) * Dd);
        const float4 v3 = *reinterpret_cast<const float4*>(vb + (size_t)(j4 * 4 + 3) * Dd);
        a0.x = fmaf(w0.x, v0.x, a0.x); a0.y = fmaf(w0.x, v0.y, a0.y);
        a0.z = fmaf(w0.x, v0.z, a0.z); a0.w = fmaf(w0.x, v0.w, a0.w);
        a1.x = fmaf(w1.x, v0.x, a1.x); a1.y = fmaf(w1.x, v0.y, a1.y);
        a1.z = fmaf(w1.x, v0.z, a1.z); a1.w = fmaf(w1.x, v0.w, a1.w);
        a0.x = fmaf(w0.y, v1.x, a0.x); a0.y = fmaf(w0.y, v1.y, a0.y);
        a0.z = fmaf(w0.y, v1.z, a0.z); a0.w = fmaf(w0.y, v1.w, a0.w);
        a1.x = fmaf(w1.y, v1.x, a1.x); a1.y = fmaf(w1.y, v1.y, a1.y);
        a1.z = fmaf(w1.y, v1.z, a1.z); a1.w = fmaf(w1.y, v1.w, a1.w);
        a0.x = fmaf(w0.z, v2.x, a0.x); a0.y = fmaf(w0.z, v2.y, a0.y);
        a0.z = fmaf(w0.z, v2.z, a0.z); a0.w = fmaf(w0.z, v2.w, a0.w);
        a1.x = fmaf(w1.z, v2.x, a1.x); a1.y = fmaf(w1.z, v2.y, a1.y);
        a1.z = fmaf(w1.z, v2.z, a1.z); a1.w = fmaf(w1.z, v2.w, a1.w);
        a0.x = fmaf(w0.w, v3.x, a0.x); a0.y = fmaf(w0.w, v3.y, a0.y);
        a0.z = fmaf(w0.w, v3.z, a0.z); a0.w = fmaf(w0.w, v3.w, a0.w);
        a1.x = fmaf(w1.w, v3.x, a1.x); a1.y = fmaf(w1.w, v3.y, a1.y);
        a1.z = fmaf(w1.w, v3.z, a1.z); a1.w = fmaf(w1.w, v3.w, a1.w);
    }
    const float iv0 = inv8[i0], iv1 = inv8[i1];
    float4 o0, o1;
    o0.x = a0.x * iv0; o0.y = a0.y * iv0; o0.z = a0.z * iv0; o0.w = a0.w * iv0;
    o1.x = a1.x * iv1; o1.y = a1.y * iv1; o1.z = a1.z * iv1; o1.w = a1.w * iv1;
    *reinterpret_cast<float4*>(out + (size_t)(r0 + i0) * Dd + d0) = o0;
    *reinterpret_cast<float4*>(out + (size_t)(r0 + i1) * Dd + d0) = o1;
}

extern "C" void kernel_launch(void* const* d_in, const int* in_sizes, int n_in,
                              void* d_out, int out_size, void* d_ws, size_t ws_size,
                              hipStream_t stream)
{
    const float* query = (const float*)d_in[0];
    const float* key   = (const float*)d_in[1];
    const float* value = (const float*)d_in[2];
    const int*   mask  = (const int*)d_in[3];     // proven int32 (R2 bit-identical)
    const float* Wa    = (const float*)d_in[4];
    const float* Ua    = (const float*)d_in[5];
    const float* scale = (const float*)d_in[6];
    float* out = (float*)d_out;

    float* qf2 = (float*)d_ws;                    // [4096,128] = 2 MB (premult)
    float* kT  = qf2 + Bb * Tq * Uu;              // [8][128][512] = 2 MB (premult, transposed)

    proj_kernel<<<(2 * Bb * Tq) / 16, 256, 0, stream>>>(query, key, Wa, Ua, qf2, kT);
    attn_kernel<<<(Bb * Tq) / 8, 512, 0, stream>>>(qf2, kT, value, mask, scale, out);
}